// Round 1
// baseline (2365.251 us; speedup 1.0000x reference)
//
#include <hip/hip_runtime.h>
#include <hip/hip_bf16.h>
#include <math.h>

#define M_  4
#define N_  50000
#define E_  400000
#define IN_ 128
#define C_  128
#define HID_ 256

// ---------------------------------------------------------------------------
// Generic tiled f32 GEMM: out[r, c] = EPI(sum_k A(r,k)*B[k*NC+c] + bias[c])
// AMODE 0: A[r*K+k]
// AMODE 1: A[r*K+k] - A2[r*K+k]            (feat_diff = out1 - xd)
// AMODE 2: A[(k>>7)*strideM + r*128 + (k&127)]   (gate_in view of feats[M,N,C])
// EPI 0: none   1: relu   2: sigmoid   3: Cmat[r,c] += rowscale[r]*(acc+bias)
// Requires: K % 16 == 0, NC % 64 == 0. R arbitrary (row guards).
// ---------------------------------------------------------------------------
template<int AMODE, int EPI>
__global__ void __launch_bounds__(256) gemm_k(
    const float* __restrict__ A, const float* __restrict__ A2,
    const float* __restrict__ B, const float* __restrict__ bias,
    float* __restrict__ Cmat, const float* __restrict__ rowscale,
    int R, int K, int NC, long long strideM)
{
  __shared__ float As[64][16];
  __shared__ float Bs[16][64];
  const int tid = threadIdx.x;
  const int tx = tid & 15, ty = tid >> 4;
  const int rb = blockIdx.y * 64, cb = blockIdx.x * 64;
  const int lrow = tid >> 2;          // 0..63
  const int lkq  = (tid & 3) * 4;     // 0,4,8,12
  const int bk   = tid >> 4;          // 0..15
  const int bnq  = (tid & 15) * 4;    // 0..60

  float acc[4][4];
  #pragma unroll
  for (int i = 0; i < 4; ++i)
    #pragma unroll
    for (int j = 0; j < 4; ++j) acc[i][j] = 0.f;

  for (int k0 = 0; k0 < K; k0 += 16) {
    // ---- load A tile (64 rows x 16 k) ----
    {
      int r = rb + lrow;
      float4 av = make_float4(0.f, 0.f, 0.f, 0.f);
      if (r < R) {
        if (AMODE == 0) {
          av = *(const float4*)(A + (long long)r * K + k0 + lkq);
        } else if (AMODE == 1) {
          float4 a1 = *(const float4*)(A  + (long long)r * K + k0 + lkq);
          float4 a2 = *(const float4*)(A2 + (long long)r * K + k0 + lkq);
          av = make_float4(a1.x - a2.x, a1.y - a2.y, a1.z - a2.z, a1.w - a2.w);
        } else {
          int kk = k0 + lkq;
          av = *(const float4*)(A + (long long)(kk >> 7) * strideM
                                  + (long long)r * 128 + (kk & 127));
        }
      }
      *(float4*)(&As[lrow][lkq]) = av;
    }
    // ---- load B tile (16 k x 64 cols) ----
    {
      float4 bv = *(const float4*)(B + (long long)(k0 + bk) * NC + cb + bnq);
      *(float4*)(&Bs[bk][bnq]) = bv;
    }
    __syncthreads();
    #pragma unroll
    for (int kk = 0; kk < 16; ++kk) {
      float a0 = As[ty * 4 + 0][kk];
      float a1 = As[ty * 4 + 1][kk];
      float a2 = As[ty * 4 + 2][kk];
      float a3 = As[ty * 4 + 3][kk];
      float4 b = *(float4*)(&Bs[kk][tx * 4]);
      acc[0][0] += a0 * b.x; acc[0][1] += a0 * b.y; acc[0][2] += a0 * b.z; acc[0][3] += a0 * b.w;
      acc[1][0] += a1 * b.x; acc[1][1] += a1 * b.y; acc[1][2] += a1 * b.z; acc[1][3] += a1 * b.w;
      acc[2][0] += a2 * b.x; acc[2][1] += a2 * b.y; acc[2][2] += a2 * b.z; acc[2][3] += a2 * b.w;
      acc[3][0] += a3 * b.x; acc[3][1] += a3 * b.y; acc[3][2] += a3 * b.z; acc[3][3] += a3 * b.w;
    }
    __syncthreads();
  }

  #pragma unroll
  for (int i = 0; i < 4; ++i) {
    int r = rb + ty * 4 + i;
    if (r >= R) break;
    float rs = 0.f;
    if (EPI == 3) rs = rowscale[r];
    if (EPI == 3 && rs == 0.f) continue;
    #pragma unroll
    for (int j = 0; j < 4; ++j) {
      int c = cb + tx * 4 + j;
      float v = acc[i][j] + bias[c];
      if (EPI == 1) v = fmaxf(v, 0.f);
      if (EPI == 2) v = 1.f / (1.f + expf(-v));
      if (EPI == 3) Cmat[(long long)r * NC + c] += rs * v;
      else          Cmat[(long long)r * NC + c] = v;
    }
  }
}

// a[m*Nn + n] = dot(X[row(n)], lin[m*128 ..])  ; perM: row = m*Nn+n else n
__global__ void attn_logit_kernel(const float* __restrict__ X, const float* __restrict__ lin,
                                  float* __restrict__ out, int Nn, int perM)
{
  int m = blockIdx.y;
  int w = blockIdx.x * (blockDim.x >> 6) + (threadIdx.x >> 6);
  int lane = threadIdx.x & 63;
  if (w >= Nn) return;
  long long row = perM ? ((long long)m * Nn + w) : (long long)w;
  const float* xr = X + row * 128;
  const float* lr = lin + m * 128;
  float acc = xr[lane] * lr[lane] + xr[lane + 64] * lr[lane + 64];
  #pragma unroll
  for (int off = 32; off > 0; off >>= 1) acc += __shfl_down(acc, off);
  if (lane == 0) out[(long long)m * Nn + w] = acc;
}

// ---- CSR build ----
__global__ void count_kernel(const int* __restrict__ dst, int* __restrict__ cnt, int Nn)
{
  int e = blockIdx.x * blockDim.x + threadIdx.x;
  int m = blockIdx.y;
  if (e >= E_) return;
  atomicAdd(&cnt[(long long)m * Nn + dst[(long long)m * E_ + e]], 1);
}

__global__ void scan_kernel(const int* __restrict__ cnt, int* __restrict__ rowptr, int Nn)
{
  __shared__ int sd[1024];
  int m = blockIdx.x;
  int tid = threadIdx.x;
  const int* c = cnt + (long long)m * Nn;
  int* rp = rowptr + (long long)m * (Nn + 1);
  if (tid == 0) rp[0] = 0;
  int running = 0;
  for (int base = 0; base < Nn; base += 1024) {
    int i = base + tid;
    int v = (i < Nn) ? c[i] : 0;
    sd[tid] = v;
    __syncthreads();
    for (int off = 1; off < 1024; off <<= 1) {
      int t = (tid >= off) ? sd[tid - off] : 0;
      __syncthreads();
      sd[tid] += t;
      __syncthreads();
    }
    if (i < Nn) rp[i + 1] = running + sd[tid];
    int tot = sd[1023];
    __syncthreads();
    running += tot;
  }
}

__global__ void scatter_kernel(const int* __restrict__ dst, const int* __restrict__ rowptr,
                               int* __restrict__ fill, int* __restrict__ col, int Nn)
{
  int e = blockIdx.x * blockDim.x + threadIdx.x;
  int m = blockIdx.y;
  if (e >= E_) return;
  int d = dst[(long long)m * E_ + e];
  int pos = rowptr[(long long)m * (Nn + 1) + d] + atomicAdd(&fill[(long long)m * Nn + d], 1);
  col[(long long)m * E_ + pos] = e;   // store edge id
}

// per-bucket insertion sort by edge id -> deterministic, np edge order
__global__ void sortbucket_kernel(const int* __restrict__ rowptr, int* __restrict__ col, int Nn)
{
  int n = blockIdx.x * blockDim.x + threadIdx.x;
  int m = blockIdx.y;
  if (n >= Nn) return;
  const int* rp = rowptr + (long long)m * (Nn + 1);
  int* c = col + (long long)m * E_;
  int b = rp[n], e = rp[n + 1];
  for (int i = b + 1; i < e; ++i) {
    int v = c[i]; int j = i - 1;
    while (j >= b && c[j] > v) { c[j + 1] = c[j]; --j; }
    c[j + 1] = v;
  }
}

// fused GAT propagation for one edge type (gather, no atomics)
__global__ void prop_kernel(const float* __restrict__ xsm, const float* __restrict__ asrcm,
                            const float* __restrict__ adstm, const int* __restrict__ rp,
                            const int* __restrict__ colm, const int* __restrict__ srcm,
                            const float* __restrict__ receptm, float* __restrict__ outm,
                            int do_relu)
{
  int d = blockIdx.x;
  int c = threadIdx.x;   // 128
  int b = rp[d], en = rp[d + 1];
  long long obase = (long long)d * 128 + c;
  if (b == en) { outm[obase] = 0.f; return; }
  float ad = adstm[d];
  float emax = -INFINITY;
  for (int j = b; j < en; ++j) {
    int s = srcm[colm[j]];
    float e = asrcm[s] + ad;
    e = (e >= 0.f) ? e : 0.2f * e;
    emax = fmaxf(emax, e);
  }
  float den = 0.f, acc = 0.f;
  for (int j = b; j < en; ++j) {
    int s = srcm[colm[j]];
    float e = asrcm[s] + ad;
    e = (e >= 0.f) ? e : 0.2f * e;
    float ez = expf(e - emax);
    den += ez;
    acc += ez * xsm[(long long)s * 128 + c];
  }
  float r = receptm ? receptm[d] : 1.f;
  float v = acc * (r / (den + 1e-16f));
  if (do_relu) v = fmaxf(v, 0.f);
  outm[obase] = v;
}

// gd = mean_c(mo * (out1 - xd)); recept = gd/(|gd|+1e-8)
__global__ void gd_kernel(const float* __restrict__ mo, const float* __restrict__ out1,
                          const float* __restrict__ xd, float* __restrict__ recept)
{
  int n = blockIdx.x;
  int c = threadIdx.x;  // 128
  long long idx = (long long)n * 128 + c;
  float fd = out1[idx] - xd[idx];
  float v = mo[idx] * fd;
  __shared__ float red[128];
  red[c] = v;
  __syncthreads();
  for (int off = 64; off > 0; off >>= 1) {
    if (c < off) red[c] += red[c + off];
    __syncthreads();
  }
  if (c == 0) {
    float gd = red[0] / 128.f;
    recept[n] = gd / (fabsf(gd) + 1e-8f);
  }
}

// logits[n, 0..3] = h[n,0..255] @ W2[256,4] + b2
__global__ void gate_logits_kernel(const float* __restrict__ h, const float* __restrict__ W2,
                                   const float* __restrict__ b2, float* __restrict__ logits, int Nn)
{
  int w = blockIdx.x * (blockDim.x >> 6) + (threadIdx.x >> 6);
  int lane = threadIdx.x & 63;
  if (w >= Nn) return;
  const float* hr = h + (long long)w * 256;
  float a0 = 0.f, a1 = 0.f, a2 = 0.f, a3 = 0.f;
  for (int j = lane; j < 256; j += 64) {
    float hv = hr[j];
    a0 += hv * W2[j * 4 + 0];
    a1 += hv * W2[j * 4 + 1];
    a2 += hv * W2[j * 4 + 2];
    a3 += hv * W2[j * 4 + 3];
  }
  #pragma unroll
  for (int off = 32; off > 0; off >>= 1) {
    a0 += __shfl_down(a0, off);
    a1 += __shfl_down(a1, off);
    a2 += __shfl_down(a2, off);
    a3 += __shfl_down(a3, off);
  }
  if (lane == 0) {
    long long o = (long long)w * 4;
    logits[o + 0] = a0 + b2[0];
    logits[o + 1] = a1 + b2[1];
    logits[o + 2] = a2 + b2[2];
    logits[o + 3] = a3 + b2[3];
  }
}

// softmax + recept.T + top-2 (jax tie rule: lower index first) -> wsel[M,N]
__global__ void topk_kernel(const float* __restrict__ logits, const float* __restrict__ recept,
                            float* __restrict__ wsel, int Nn)
{
  int n = blockIdx.x * blockDim.x + threadIdx.x;
  if (n >= Nn) return;
  float l[4];
  #pragma unroll
  for (int m = 0; m < 4; ++m) l[m] = logits[(long long)n * 4 + m];
  float mx = fmaxf(fmaxf(l[0], l[1]), fmaxf(l[2], l[3]));
  float e[4], s = 0.f;
  #pragma unroll
  for (int m = 0; m < 4; ++m) { e[m] = expf(l[m] - mx); s += e[m]; }
  float sc[4];
  #pragma unroll
  for (int m = 0; m < 4; ++m) sc[m] = e[m] / s + recept[(long long)m * Nn + n];
  int i0 = 0; float v0 = sc[0];
  #pragma unroll
  for (int m = 1; m < 4; ++m) if (sc[m] > v0) { v0 = sc[m]; i0 = m; }
  int i1 = -1; float v1 = -INFINITY;
  #pragma unroll
  for (int m = 0; m < 4; ++m) { if (m == i0) continue; if (sc[m] > v1) { v1 = sc[m]; i1 = m; } }
  float ts = v0 + v1;
  float w0 = v0 / ts, w1 = v1 / ts;
  #pragma unroll
  for (int m = 0; m < 4; ++m)
    wsel[(long long)m * Nn + n] = (m == i0) ? w0 : ((m == i1) ? w1 : 0.f);
}

extern "C" void kernel_launch(void* const* d_in, const int* in_sizes, int n_in,
                              void* d_out, int out_size, void* d_ws, size_t ws_size,
                              hipStream_t stream) {
  const float* x_src   = (const float*)d_in[0];
  const float* x_dst   = (const float*)d_in[1];
  const int*   src_idx = (const int*)d_in[2];
  const int*   dst_idx = (const int*)d_in[3];
  const float* proj_Ws = (const float*)d_in[4];
  const float* proj_bs = (const float*)d_in[5];
  const float* projd_W = (const float*)d_in[6];
  const float* projd_b = (const float*)d_in[7];
  const float* lin_src = (const float*)d_in[8];
  const float* lin_dst = (const float*)d_in[9];
  const float* gm_W1   = (const float*)d_in[10];
  const float* gm_b1   = (const float*)d_in[11];
  const float* gm_W2   = (const float*)d_in[12];
  const float* gm_b2   = (const float*)d_in[13];
  const float* gate_W1 = (const float*)d_in[14];
  const float* gate_b1 = (const float*)d_in[15];
  const float* gate_W2 = (const float*)d_in[16];
  const float* gate_b2 = (const float*)d_in[17];
  const float* exp_W1  = (const float*)d_in[18];
  const float* exp_b1  = (const float*)d_in[19];
  const float* exp_W2  = (const float*)d_in[20];
  const float* exp_b2  = (const float*)d_in[21];
  float* final_out = (float*)d_out;

  float* ws = (float*)d_ws;
  float* xs     = ws;                        // [M,N,C]      25,600,000
  float* feats  = ws + 25600000LL;           // [M,N,C]      25,600,000 (out1 -> out2/feats)
  float* xd     = ws + 51200000LL;           // [N,C]         6,400,000
  float* tbuf   = ws + 57600000LL;           // [N,HID]      12,800,000
  float* mo     = tbuf + 6400000LL;          // [N,C] overlay in tbuf upper half
  float* asrc   = ws + 70400000LL;           // [M,N]
  float* adst   = ws + 70600000LL;           // [M,N]
  float* recept = ws + 70800000LL;           // [M,N]
  float* wsel   = ws + 71000000LL;           // [M,N]
  float* logits = ws + 71200000LL;           // [N,4]
  int*   ibase  = (int*)(ws + 71400000LL);
  int*   rowptr = ibase;                     // [M,(N+1)]
  int*   col    = ibase + 200004;            // [M,E]
  int*   cnt    = ibase + 1800004;           // [M,N]

  const long long NC = (long long)N_ * C_;

  hipMemsetAsync(d_out, 0, (size_t)out_size * sizeof(float), stream);

  // ---- CSR build (all m) ----
  hipMemsetAsync(cnt, 0, (size_t)M_ * N_ * sizeof(int), stream);
  count_kernel<<<dim3((E_ + 255) / 256, M_), 256, 0, stream>>>(dst_idx, cnt, N_);
  scan_kernel<<<M_, 1024, 0, stream>>>(cnt, rowptr, N_);
  hipMemsetAsync(cnt, 0, (size_t)M_ * N_ * sizeof(int), stream);
  scatter_kernel<<<dim3((E_ + 255) / 256, M_), 256, 0, stream>>>(dst_idx, rowptr, cnt, col, N_);
  sortbucket_kernel<<<dim3((N_ + 255) / 256, M_), 256, 0, stream>>>(rowptr, col, N_);

  dim3 g128(C_ / 64, (N_ + 63) / 64);        // NC=128
  dim3 g256(HID_ / 64, (N_ + 63) / 64);      // NC=256

  // ---- xd = x_dst @ projd_W + b ----
  gemm_k<0, 0><<<g128, 256, 0, stream>>>(x_dst, nullptr, projd_W, projd_b, xd, nullptr,
                                         N_, IN_, C_, 0);
  // a_dst[m,n]
  attn_logit_kernel<<<dim3((N_ + 3) / 4, M_), 256, 0, stream>>>(xd, lin_dst, adst, N_, 0);

  // ---- per-type projection + a_src ----
  for (int m = 0; m < M_; ++m) {
    gemm_k<0, 0><<<g128, 256, 0, stream>>>(x_src + (long long)m * N_ * IN_, nullptr,
                                           proj_Ws + (long long)m * IN_ * C_,
                                           proj_bs + (long long)m * C_,
                                           xs + m * NC, nullptr, N_, IN_, C_, 0);
  }
  attn_logit_kernel<<<dim3((N_ + 3) / 4, M_), 256, 0, stream>>>(xs, lin_src, asrc, N_, 1);

  // ---- pass 1: out1 (stored in feats) ----
  for (int m = 0; m < M_; ++m) {
    prop_kernel<<<N_, 128, 0, stream>>>(xs + m * NC, asrc + (long long)m * N_,
                                        adst + (long long)m * N_,
                                        rowptr + (long long)m * (N_ + 1),
                                        col + (long long)m * E_,
                                        src_idx + (long long)m * E_,
                                        nullptr, feats + m * NC, 0);
  }

  // ---- grad-map MLP -> recept ----
  for (int m = 0; m < M_; ++m) {
    gemm_k<1, 1><<<g128, 256, 0, stream>>>(feats + m * NC, xd, gm_W1, gm_b1,
                                           tbuf, nullptr, N_, C_, C_, 0);
    gemm_k<0, 2><<<g128, 256, 0, stream>>>(tbuf, nullptr, gm_W2, gm_b2,
                                           mo, nullptr, N_, C_, C_, 0);
    gd_kernel<<<N_, 128, 0, stream>>>(mo, feats + m * NC, xd, recept + (long long)m * N_);
  }

  // ---- pass 2: out2 -> relu -> feats ----
  for (int m = 0; m < M_; ++m) {
    prop_kernel<<<N_, 128, 0, stream>>>(xs + m * NC, asrc + (long long)m * N_,
                                        adst + (long long)m * N_,
                                        rowptr + (long long)m * (N_ + 1),
                                        col + (long long)m * E_,
                                        src_idx + (long long)m * E_,
                                        recept + (long long)m * N_, feats + m * NC, 1);
  }

  // ---- gate: hidden = relu(gate_in @ W1 + b1), gate_in strided view of feats ----
  gemm_k<2, 1><<<g256, 256, 0, stream>>>(feats, nullptr, gate_W1, gate_b1,
                                         tbuf, nullptr, N_, M_ * C_, HID_, NC);
  gate_logits_kernel<<<dim3((N_ + 3) / 4), 256, 0, stream>>>(tbuf, gate_W2, gate_b2, logits, N_);
  topk_kernel<<<(N_ + 255) / 256, 256, 0, stream>>>(logits, recept, wsel, N_);

  // ---- experts (dense per type, weighted accumulate into final) ----
  for (int m = 0; m < M_; ++m) {
    gemm_k<0, 1><<<g256, 256, 0, stream>>>(feats + m * NC, nullptr,
                                           exp_W1 + (long long)m * C_ * HID_,
                                           exp_b1 + (long long)m * HID_,
                                           tbuf, nullptr, N_, C_, HID_, 0);
    gemm_k<0, 3><<<g128, 256, 0, stream>>>(tbuf, nullptr,
                                           exp_W2 + (long long)m * HID_ * C_,
                                           exp_b2 + (long long)m * C_,
                                           final_out, wsel + (long long)m * N_,
                                           N_, HID_, C_, 0);
  }
}